// Round 10
// baseline (374.893 us; speedup 1.0000x reference)
//
#include <hip/hip_runtime.h>

typedef unsigned short u16;
typedef unsigned int   u32;
typedef __bf16 bf16x8 __attribute__((ext_vector_type(8)));
typedef float  f32x4  __attribute__((ext_vector_type(4)));

__device__ __forceinline__ float b2f(u16 s) { return __uint_as_float(((u32)s) << 16); }
__device__ __forceinline__ u16 f2b(float f) {
  u32 x = __float_as_uint(f);
  return (u16)((x + 0x7FFFu + ((x >> 16) & 1u)) >> 16);  // RNE, finite inputs only
}

#if __has_builtin(__builtin_amdgcn_exp2f)
#define EXP2(x) __builtin_amdgcn_exp2f(x)
#else
#define EXP2(x) exp2f(x)
#endif

// DPP 16-lane rotate-reduce (VALU pipe, no LDS) — row_ror:8/4/2/1
template <int C>
__device__ __forceinline__ u32 dppu(u32 s) {
  return (u32)__builtin_amdgcn_update_dpp((int)s, (int)s, C, 0xF, 0xF, false);
}
__device__ __forceinline__ float red_sum16(float x) {
  x += __uint_as_float(dppu<0x128>(__float_as_uint(x)));
  x += __uint_as_float(dppu<0x124>(__float_as_uint(x)));
  x += __uint_as_float(dppu<0x122>(__float_as_uint(x)));
  x += __uint_as_float(dppu<0x121>(__float_as_uint(x)));
  return x;
}

union U16x8 { uint4 u; u16 s[8]; };

__device__ __forceinline__ uint4 cvt8(const float4 a, const float4 b) {
  U16x8 r;
  r.s[0] = f2b(a.x); r.s[1] = f2b(a.y); r.s[2] = f2b(a.z); r.s[3] = f2b(a.w);
  r.s[4] = f2b(b.x); r.s[5] = f2b(b.y); r.s[6] = f2b(b.z); r.s[7] = f2b(b.w);
  return r.u;
}

// async global->LDS, 16B per lane. LDS dest is wave-uniform base + lane*16.
typedef __attribute__((address_space(3))) u32 lds_u32;
typedef const __attribute__((address_space(1))) u32 glb_u32;
__device__ __forceinline__ void gld16(const u16* gp, u16* lp) {
  __builtin_amdgcn_global_load_lds((glb_u32*)gp, (lds_u32*)lp, 16, 0, 0);
}

// ---------------------------------------------------------------------------
// f32 -> bf16 bulk convert (8 tensors in one launch; blockIdx.y = tensor id)
// ---------------------------------------------------------------------------
struct CvtArgs { const float* s[8]; u16* d[8]; int n[8]; };

__global__ __launch_bounds__(256) void cvt_bf16(CvtArgs c) {
  const int t = blockIdx.y;
  const int i = (blockIdx.x * 256 + threadIdx.x) * 8;
  if (i >= c.n[t]) return;
  const float4 a = *(const float4*)(c.s[t] + i);
  const float4 b = *(const float4*)(c.s[t] + i + 4);
  *(uint4*)(c.d[t] + i) = cvt8(a, b);
}

// ---------------------------------------------------------------------------
// m97-style bf16 GEMM: C[z] = A[z] (MxK bf16) @ W[z]^T (NxK bf16) + bias (f32)
// ---------------------------------------------------------------------------
struct GemmBArgs { const u16* A[5]; const u16* W[5]; const float* Bi[5]; void* C[5]; int vtz; };

template <int BN, bool OUT_F32>
__global__ __launch_bounds__(256) void gemm_lds(GemmBArgs g, int M, int N, int K) {
  const int z = blockIdx.z;
  const u16* __restrict__ A = g.A[z];
  const u16* __restrict__ W = g.W[z];
  const float* __restrict__ Bi = g.Bi[z];

  const int m0 = blockIdx.y * 128, n0 = blockIdx.x * BN;
  const int tid = threadIdx.x, wv = tid >> 6, lane = tid & 63;
  const int wm = wv >> 1, wn = wv & 1;
  const int lr = lane & 15, lq = lane >> 4;
  constexpr int NT = BN / 32;

  __shared__ u16 As[128 * 64];
  __shared__ u16 Ws[BN * 64];

  const f32x4 vzero = {0.f, 0.f, 0.f, 0.f};
  f32x4 acc[4][NT];
#pragma unroll
  for (int i = 0; i < 4; ++i)
#pragma unroll
    for (int j = 0; j < NT; ++j) acc[i][j] = vzero;

  const int srow = lane >> 3;                 // 0..7
  const int sc   = (lane & 7) ^ srow;         // swizzled 16B chunk index

  for (int kb = 0; kb < K; kb += 64) {
    __syncthreads();
#pragma unroll
    for (int t = 0; t < 4; ++t) {
      const u16* gp = A + (size_t)(m0 + t * 32 + wv * 8 + srow) * K + kb + sc * 8;
      gld16(gp, As + (t * 32 + wv * 8) * 64 + lane * 8);
    }
#pragma unroll
    for (int t = 0; t < NT; ++t) {
      const u16* gp = W + (size_t)(n0 + t * 32 + wv * 8 + srow) * K + kb + sc * 8;
      gld16(gp, Ws + (t * 32 + wv * 8) * 64 + lane * 8);
    }
    __syncthreads();
#pragma unroll
    for (int kk = 0; kk < 2; ++kk) {
      bf16x8 af[4], bw[NT];
#pragma unroll
      for (int mt = 0; mt < 4; ++mt) {
        const int row = wm * 64 + mt * 16 + lr;
        af[mt] = *(const bf16x8*)&As[row * 64 + (((kk << 2) | lq) ^ (row & 7)) * 8];
      }
#pragma unroll
      for (int nt = 0; nt < NT; ++nt) {
        const int row = wn * (BN / 2) + nt * 16 + lr;
        bw[nt] = *(const bf16x8*)&Ws[row * 64 + (((kk << 2) | lq) ^ (row & 7)) * 8];
      }
#pragma unroll
      for (int mt = 0; mt < 4; ++mt)
#pragma unroll
        for (int nt = 0; nt < NT; ++nt)
          acc[mt][nt] = __builtin_amdgcn_mfma_f32_16x16x32_bf16(af[mt], bw[nt], acc[mt][nt], 0, 0, 0);
    }
  }

#pragma unroll
  for (int mt = 0; mt < 4; ++mt) {
#pragma unroll
    for (int nt = 0; nt < NT; ++nt) {
      const int col = n0 + wn * (BN / 2) + nt * 16 + lr;
      const float bia = Bi[col];
      const int row0 = m0 + wm * 64 + mt * 16 + lq * 4;
      if (OUT_F32) {
#pragma unroll
        for (int r = 0; r < 4; ++r)
          ((float*)g.C[z])[(size_t)(row0 + r) * N + col] = acc[mt][nt][r] + bia;
      } else if (z == g.vtz) {
        ushort4 pk;
        pk.x = f2b(acc[mt][nt][0] + bia); pk.y = f2b(acc[mt][nt][1] + bia);
        pk.z = f2b(acc[mt][nt][2] + bia); pk.w = f2b(acc[mt][nt][3] + bia);
        const int bb = row0 >> 10, s0 = row0 & 1023;
        *(ushort4*)((u16*)g.C[z] + ((size_t)bb << 20) + ((size_t)col << 10) + s0) = pk;
      } else {
#pragma unroll
        for (int r = 0; r < 4; ++r)
          ((u16*)g.C[z])[(size_t)(row0 + r) * N + col] = f2b(acc[mt][nt][r] + bia);
      }
    }
  }
}

// ---------------------------------------------------------------------------
// Fallback GEMM (ws too small for pre-convert): f32 stage-convert, proven R2.
// ---------------------------------------------------------------------------
struct GemmArgs { const void* A[5]; const float* W[5]; const float* Bi[5]; void* C[5]; int vtz; };

template <bool A_F32, bool OUT_F32>
__global__ __launch_bounds__(256) void gemm5(GemmArgs g, int M, int N, int K) {
  const int z = blockIdx.z;
  const float* __restrict__ Wf = g.W[z];
  const float* __restrict__ Bi = g.Bi[z];

  const int m0 = blockIdx.y * 128, n0 = blockIdx.x * 128;
  const int tid = threadIdx.x;
  const int wv = tid >> 6, lane = tid & 63;
  const int wm = wv >> 1, wn = wv & 1;
  const int lr = lane & 15, lq = lane >> 4;

  __shared__ alignas(16) u16 As[128][64];
  __shared__ alignas(16) u16 Ws[128][64];

  const f32x4 vzero = {0.f, 0.f, 0.f, 0.f};
  f32x4 acc[4][4];
#pragma unroll
  for (int i = 0; i < 4; ++i)
#pragma unroll
    for (int j = 0; j < 4; ++j) acc[i][j] = vzero;

  const int srow = tid >> 1;
  const int sc0  = (tid & 1) * 32;
  const float* pw = Wf + (size_t)(n0 + srow) * K + sc0;
  const float* paf = A_F32 ? ((const float*)g.A[z] + (size_t)(m0 + srow) * K + sc0) : nullptr;
  const u16*   pab = A_F32 ? nullptr : ((const u16*)g.A[z] + (size_t)(m0 + srow) * K + sc0);

  for (int k0 = 0; k0 < K; k0 += 64) {
#pragma unroll
    for (int u_ = 0; u_ < 4; ++u_) {
      const float4 w0 = *(const float4*)(pw + k0 + u_ * 8);
      const float4 w1 = *(const float4*)(pw + k0 + u_ * 8 + 4);
      *(uint4*)&Ws[srow][sc0 + u_ * 8] = cvt8(w0, w1);
      if (A_F32) {
        const float4 a0 = *(const float4*)(paf + k0 + u_ * 8);
        const float4 a1 = *(const float4*)(paf + k0 + u_ * 8 + 4);
        *(uint4*)&As[srow][sc0 + u_ * 8] = cvt8(a0, a1);
      } else {
        *(uint4*)&As[srow][sc0 + u_ * 8] = *(const uint4*)(pab + k0 + u_ * 8);
      }
    }
    __syncthreads();
#pragma unroll
    for (int kk = 0; kk < 2; ++kk) {
      bf16x8 af[4], bfr[4];
#pragma unroll
      for (int mt = 0; mt < 4; ++mt)
        af[mt] = *(const bf16x8*)&As[wm * 64 + mt * 16 + lr][kk * 32 + lq * 8];
#pragma unroll
      for (int nt = 0; nt < 4; ++nt)
        bfr[nt] = *(const bf16x8*)&Ws[wn * 64 + nt * 16 + lr][kk * 32 + lq * 8];
#pragma unroll
      for (int mt = 0; mt < 4; ++mt)
#pragma unroll
        for (int nt = 0; nt < 4; ++nt)
          acc[mt][nt] = __builtin_amdgcn_mfma_f32_16x16x32_bf16(af[mt], bfr[nt], acc[mt][nt], 0, 0, 0);
    }
    __syncthreads();
  }

#pragma unroll
  for (int mt = 0; mt < 4; ++mt) {
#pragma unroll
    for (int nt = 0; nt < 4; ++nt) {
      const int col = n0 + wn * 64 + nt * 16 + lr;
      const float bia = Bi[col];
      const int row0 = m0 + wm * 64 + mt * 16 + lq * 4;
      if (OUT_F32) {
#pragma unroll
        for (int r = 0; r < 4; ++r)
          ((float*)g.C[z])[(size_t)(row0 + r) * N + col] = acc[mt][nt][r] + bia;
      } else if (z == g.vtz) {
        ushort4 pk;
        pk.x = f2b(acc[mt][nt][0] + bia); pk.y = f2b(acc[mt][nt][1] + bia);
        pk.z = f2b(acc[mt][nt][2] + bia); pk.w = f2b(acc[mt][nt][3] + bia);
        const int bb = row0 >> 10, s0 = row0 & 1023;
        *(ushort4*)((u16*)g.C[z] + ((size_t)bb << 20) + ((size_t)col << 10) + s0) = pk;
      } else {
#pragma unroll
        for (int r = 0; r < 4; ++r)
          ((u16*)g.C[z])[(size_t)(row0 + r) * N + col] = f2b(acc[mt][nt][r] + bia);
      }
    }
  }
}

// ---------------------------------------------------------------------------
// Barrier-free per-wave disentangled attention, v7.
// v6 (no-max softmax) + occupancy push to 3 waves/SIMD:
//   - __launch_bounds__(256,3): cap total regs at 170 (R9 measured ~176 total
//     = 128 arch + ~48 acc -> 2 waves/SIMD; we need to shave only ~8).
//     NOT R5's mistake: (256,4) demanded <=128 vs ~176 live -> massive spill.
//   - V-fragment loads deferred to just before PV: their 16 VGPRs no longer
//     span the G-phase peak, giving the allocator the needed slack.
// Go/no-go: FETCH_SIZE must stay ~10.3e3 KB; a jump means spill -> revert.
// ---------------------------------------------------------------------------
__global__ __launch_bounds__(256, 3) void attn_wave(
    const u16* __restrict__ q, const u16* __restrict__ k,
    const u16* __restrict__ vT, const u16* __restrict__ qr,
    const u16* __restrict__ kr, const int* __restrict__ pmask,
    u16* __restrict__ ao) {
  constexpr int S = 1024, Dm = 1024;
  constexpr int GP = 37;           // f32 stride of G1f/G2f rows
  constexpr int PBP = 74;          // u16 stride of Pb rows (= one G1f row)
  constexpr int WLDS = 9472;       // per-wave LDS: 4736 (G1f+Pb alias) + 4736

  __shared__ alignas(16) char smem[4 * WLDS];

  const int bx = blockIdx.x;
  const int bh = bx & 31, it = bx >> 5;   // bh-inner => (b,h) stays on one XCD
  const int bb = bh >> 4, h = bh & 15;
  const int i0 = it * 32;

  const int tid = threadIdx.x;
  const int wv = tid >> 6, lane = tid & 63;
  const int lq = lane >> 4, lr = lane & 15;

  char* wbase = smem + wv * WLDS;
  float* G1f = (float*)wbase;              // 1184 f32: [2 pad][32 rows x 37]
  float* G2f = (float*)(wbase + 4736);     // same layout (never aliased)
  u16*   Pb  = (u16*)wbase;                // rows at 148B stride, bytes [0,64)

  const u16* qb  = q  + ((size_t)bb << 20) + h * 64;
  const u16* kb  = k  + ((size_t)bb << 20) + h * 64;
  const u16* qrb = qr + ((size_t)bb << 20) + h * 64;
  const u16* krb = kr + ((size_t)bb << 20) + h * 64;
  const u16* vtb = vT + ((size_t)bb << 20) + ((size_t)h << 16);
  const int* pmb = pmask + ((size_t)bb << 10);

  const float kscale = 1.44269504088896f / 13.856406460551018f;  // log2e/sqrt(192)

  // cached Q A-frags: rows i0 + mt*16 + lr, k-chunks kk*32 + lq*8
  bf16x8 qf[2][2];
#pragma unroll
  for (int mt = 0; mt < 2; ++mt)
#pragma unroll
    for (int kk = 0; kk < 2; ++kk)
      qf[mt][kk] = *(const bf16x8*)(qb + (size_t)(i0 + mt * 16 + lr) * Dm + kk * 32 + lq * 8);

  const f32x4 vzero = {0.f, 0.f, 0.f, 0.f};
  f32x4 o[2][4];
#pragma unroll
  for (int mt = 0; mt < 2; ++mt)
#pragma unroll
    for (int nd = 0; nd < 4; ++nd) o[mt][nd] = vzero;
  float lst[2][4];  // per-lane partial sum of P (over this lane's b columns)
#pragma unroll
  for (int mt = 0; mt < 2; ++mt)
#pragma unroll
    for (int r = 0; r < 4; ++r) lst[mt][r] = 0.f;

#pragma unroll 1
  for (int t8 = 0; t8 < 8; ++t8) {
    const int j0 = (wv + t8 * 4) * 32;
    const int pb_ = i0 - j0 + 481;  // window row t -> global row clamp(pb_ + t)

    // ---- K fragments (direct from global) ----
    bf16x8 kf[2][2];
#pragma unroll
    for (int nt = 0; nt < 2; ++nt) {
      const u16* kp = kb + (size_t)(j0 + nt * 16 + lr) * Dm + lq * 8;
      kf[nt][0] = *(const bf16x8*)kp;
      kf[nt][1] = *(const bf16x8*)(kp + 32);
    }
    const int mv0 = pmb[j0 + lr], mv1 = pmb[j0 + 16 + lr];

    // ---- c2c into registers (C-layout) ----
    f32x4 cc[2][2];
#pragma unroll
    for (int mt = 0; mt < 2; ++mt)
#pragma unroll
      for (int nt = 0; nt < 2; ++nt) {
        f32x4 a = vzero;
        a = __builtin_amdgcn_mfma_f32_16x16x32_bf16(qf[mt][0], kf[nt][0], a, 0, 0, 0);
        a = __builtin_amdgcn_mfma_f32_16x16x32_bf16(qf[mt][1], kf[nt][1], a, 0, 0, 0);
        cc[mt][nt] = a;
      }

    // ---- G1 = Q@KRw^T and G2' = K@QRw^T, per-n4 slices, redirect stores ----
#pragma unroll
    for (int n4 = 0; n4 < 4; ++n4) {
      int p = pb_ + n4 * 16 + lr;
      p = p < 0 ? 0 : (p > 1023 ? 1023 : p);
      const u16* kp = krb + (size_t)p * Dm + lq * 8;
      const u16* qp = qrb + (size_t)p * Dm + lq * 8;
      const bf16x8 kr0 = *(const bf16x8*)kp;
      const bf16x8 kr1 = *(const bf16x8*)(kp + 32);
      const bf16x8 qr0 = *(const bf16x8*)qp;
      const bf16x8 qr1 = *(const bf16x8*)(qp + 32);
      const int tb = n4 * 16 + lr;
#pragma unroll
      for (int mt = 0; mt < 2; ++mt) {
        f32x4 a = vzero;
        a = __builtin_amdgcn_mfma_f32_16x16x32_bf16(qf[mt][0], kr0, a, 0, 0, 0);
        a = __builtin_amdgcn_mfma_f32_16x16x32_bf16(qf[mt][1], kr1, a, 0, 0, 0);
#pragma unroll
        for (int r = 0; r < 4; ++r) {
          const int arow = mt * 16 + lq * 4 + r;
          int u = tb - arow;                       // valid band: [0,32)
          u = u < -2 ? -2 : (u > 34 ? 34 : u);     // invalid -> row padding
          G1f[2 + arow * GP + u] = a[r];
        }
      }
#pragma unroll
      for (int mt = 0; mt < 2; ++mt) {
        f32x4 g = vzero;
        g = __builtin_amdgcn_mfma_f32_16x16x32_bf16(kf[mt][0], qr0, g, 0, 0, 0);
        g = __builtin_amdgcn_mfma_f32_16x16x32_bf16(kf[mt][1], qr1, g, 0, 0, 0);
#pragma unroll
        for (int r = 0; r < 4; ++r) {
          const int brow = mt * 16 + lq * 4 + r;
          int u = tb + brow - 31;                  // valid band: [0,32)
          u = u < -2 ? -2 : (u > 34 ? 34 : u);
          G2f[2 + brow * GP + u] = g[r];
        }
      }
    }

    // ---- no-max softmax (phase 1: reads G1f/G2f, no cross-lane ops) ----
    u32 pk[2][4];
#pragma unroll
    for (int mt = 0; mt < 2; ++mt) {
#pragma unroll
      for (int r = 0; r < 4; ++r) {
        const int a_ = mt * 16 + lq * 4 + r;
        float s0 = cc[mt][0][r] + G1f[2 + a_ * GP + 31 - lr] + G2f[2 + lr * GP + a_];
        float s1 = cc[mt][1][r] + G1f[2 + a_ * GP + 15 - lr] + G2f[2 + (16 + lr) * GP + a_];
        s0 = mv0 ? -1e30f : s0 * kscale;
        s1 = mv1 ? -1e30f : s1 * kscale;
        const float p0 = EXP2(s0);
        const float p1 = EXP2(s1);
        lst[mt][r] += p0 + p1;
        pk[mt][r] = (u32)f2b(p0) | ((u32)f2b(p1) << 16);
      }
    }
    __asm__ volatile("" ::: "memory");  // order: G reads above, Pb stores below
    // ---- phase 2: write Pb (aliases G1f rows) ----
#pragma unroll
    for (int mt = 0; mt < 2; ++mt)
#pragma unroll
      for (int r = 0; r < 4; ++r) {
        const int a_ = mt * 16 + lq * 4 + r;
        Pb[a_ * PBP + lr]      = (u16)pk[mt][r];
        Pb[a_ * PBP + 16 + lr] = (u16)(pk[mt][r] >> 16);
      }

    // ---- V fragments (deferred: loaded only for PV, shortens reg live span)
    bf16x8 vf[4];
#pragma unroll
    for (int n4 = 0; n4 < 4; ++n4)
      vf[n4] = *(const bf16x8*)(vtb + (size_t)(n4 * 16 + lr) * S + j0 + lq * 8);

    // ---- PV: read P A-frags, accumulate (no rescale — unnormalized) ----
#pragma unroll
    for (int mt = 0; mt < 2; ++mt) {
      union { u32 u[4]; bf16x8 v; } pr;
      const u16* prow = Pb + (mt * 16 + lr) * PBP + lq * 8;
      pr.u[0] = *(const u32*)prow;
      pr.u[1] = *(const u32*)(prow + 2);
      pr.u[2] = *(const u32*)(prow + 4);
      pr.u[3] = *(const u32*)(prow + 6);
#pragma unroll
      for (int nd = 0; nd < 4; ++nd)
        o[mt][nd] = __builtin_amdgcn_mfma_f32_16x16x32_bf16(pr.v, vf[nd], o[mt][nd], 0, 0, 0);
    }
    __asm__ volatile("" ::: "memory");  // order: Pb reads above, next-iter band stores below
  }

  // ---- dump per-wave state, merge 4 ways, write ao ----
  {
    float* Orm = (float*)wbase;            // [32][64]
    float* llw = (float*)(wbase + 8192);   // [32]
#pragma unroll
    for (int mt = 0; mt < 2; ++mt)
#pragma unroll
      for (int nd = 0; nd < 4; ++nd)
#pragma unroll
        for (int r = 0; r < 4; ++r)
          Orm[(mt * 16 + lq * 4 + r) * 64 + nd * 16 + lr] = o[mt][nd][r];
#pragma unroll
    for (int mt = 0; mt < 2; ++mt)
#pragma unroll
      for (int r = 0; r < 4; ++r) {
        const float rl = red_sum16(lst[mt][r]);   // row-total l (once, not per iter)
        if (lr == 0) llw[mt * 16 + lq * 4 + r] = rl;
      }
  }
  __syncthreads();
  {
    const int a_ = tid >> 3, d0 = (tid & 7) * 8;
    float L = 0.f, acc[8];
#pragma unroll
    for (int d = 0; d < 8; ++d) acc[d] = 0.f;
#pragma unroll
    for (int w = 0; w < 4; ++w) {
      const char* wb = smem + w * WLDS;
      L += *(const float*)(wb + 8192 + a_ * 4);
      const float* Ow = (const float*)wb + a_ * 64 + d0;
#pragma unroll
      for (int d = 0; d < 8; ++d) acc[d] += Ow[d];
    }
    const float inv = 1.f / L;
    U16x8 pk;
#pragma unroll
    for (int d = 0; d < 8; ++d) pk.s[d] = f2b(acc[d] * inv);
    *(uint4*)(ao + ((size_t)((bb << 10) + i0 + a_) << 10) + (h << 6) + d0) = pk.u;
  }
}

// ---------------------------------------------------------------------------
extern "C" void kernel_launch(void* const* d_in, const int* in_sizes, int n_in,
                              void* d_out, int out_size, void* d_ws, size_t ws_size,
                              hipStream_t stream) {
  const float* x   = (const float*)d_in[0];
  const float* rpe = (const float*)d_in[1];
  const int*   pm  = (const int*)d_in[2];
  const float* Wq  = (const float*)d_in[3];  const float* bq  = (const float*)d_in[4];
  const float* Wk  = (const float*)d_in[5];  const float* bk  = (const float*)d_in[6];
  const float* Wv  = (const float*)d_in[7];  const float* bv  = (const float*)d_in[8];
  const float* Wqr = (const float*)d_in[9];  const float* bqr = (const float*)d_in[10];
  const float* Wkr = (const float*)d_in[11]; const float* bkr = (const float*)d_in[12];
  const float* Wc  = (const float*)d_in[13]; const float* bc  = (const float*)d_in[14];

  const size_t NE = (size_t)2 * 1024 * 1024;  // B*S*D elements
  const size_t WE = (size_t)1024 * 1024;      // D*D elements
  u16* ws = (u16*)d_ws;

  if (ws_size >= (10 * NE + 6 * WE) * sizeof(u16)) {
    u16* q   = ws;          u16* k   = ws + NE;     u16* vT  = ws + 2 * NE;
    u16* qr  = ws + 3 * NE; u16* kr  = ws + 4 * NE;
    u16* xb  = ws + 5 * NE;
    u16* ao  = ws + 5 * NE;  // same slot: xb dead once proj GEMM finishes
    u16* rpb = ws + 6 * NE;
    u16* wb  = ws + 7 * NE;
    u16* Wqb = wb;           u16* Wkb = wb + WE;     u16* Wvb = wb + 2 * WE;
    u16* Wqrb= wb + 3 * WE;  u16* Wkrb= wb + 4 * WE; u16* Wcb = wb + 5 * WE;

    CvtArgs c;
    c.s[0] = x;   c.d[0] = xb;   c.n[0] = (int)NE;
    c.s[1] = rpe; c.d[1] = rpb;  c.n[1] = (int)NE;
    c.s[2] = Wq;  c.d[2] = Wqb;  c.n[2] = (int)WE;
    c.s[3] = Wk;  c.d[3] = Wkb;  c.n[3] = (int)WE;
    c.s[4] = Wv;  c.d[4] = Wvb;  c.n[4] = (int)WE;
    c.s[5] = Wqr; c.d[5] = Wqrb; c.n[5] = (int)WE;
    c.s[6] = Wkr; c.d[6] = Wkrb; c.n[6] = (int)WE;
    c.s[7] = Wc;  c.d[7] = Wcb;  c.n[7] = (int)WE;
    cvt_bf16<<<dim3(1024, 8), 256, 0, stream>>>(c);

    GemmBArgs g;
    g.A[0] = xb;  g.W[0] = Wqb;  g.Bi[0] = bq;  g.C[0] = q;
    g.A[1] = xb;  g.W[1] = Wkb;  g.Bi[1] = bk;  g.C[1] = k;
    g.A[2] = xb;  g.W[2] = Wvb;  g.Bi[2] = bv;  g.C[2] = vT;
    g.A[3] = rpb; g.W[3] = Wqrb; g.Bi[3] = bqr; g.C[3] = qr;
    g.A[4] = rpb; g.W[4] = Wkrb; g.Bi[4] = bkr; g.C[4] = kr;
    g.vtz = 2;
    gemm_lds<128, false><<<dim3(8, 16, 5), 256, 0, stream>>>(g, 2048, 1024, 1024);

    attn_wave<<<dim3(1024), 256, 0, stream>>>(q, k, vT, qr, kr, pm, ao);

    GemmBArgs g2;
    for (int i = 0; i < 5; ++i) { g2.A[i] = ao; g2.W[i] = Wcb; g2.Bi[i] = bc; g2.C[i] = d_out; }
    g2.vtz = -1;
    gemm_lds<64, true><<<dim3(16, 16, 1), 256, 0, stream>>>(g2, 2048, 1024, 1024);
  } else {
    if (ws_size < 6 * NE * sizeof(u16)) return;
    u16* q  = ws;          u16* k  = ws + NE;     u16* vT = ws + 2 * NE;
    u16* qr = ws + 3 * NE; u16* kr = ws + 4 * NE; u16* ao = ws + 5 * NE;

    GemmArgs g;
    g.A[0] = x;   g.W[0] = Wq;  g.Bi[0] = bq;  g.C[0] = q;
    g.A[1] = x;   g.W[1] = Wk;  g.Bi[1] = bk;  g.C[1] = k;
    g.A[2] = x;   g.W[2] = Wv;  g.Bi[2] = bv;  g.C[2] = vT;
    g.A[3] = rpe; g.W[3] = Wqr; g.Bi[3] = bqr; g.C[3] = qr;
    g.A[4] = rpe; g.W[4] = Wkr; g.Bi[4] = bkr; g.C[4] = kr;
    g.vtz = 2;
    gemm5<true, false><<<dim3(8, 16, 5), 256, 0, stream>>>(g, 2048, 1024, 1024);

    attn_wave<<<dim3(1024), 256, 0, stream>>>(q, k, vT, qr, kr, pm, ao);

    GemmArgs g2;
    for (int i = 0; i < 5; ++i) { g2.A[i] = ao; g2.W[i] = Wc; g2.Bi[i] = bc; g2.C[i] = d_out; }
    g2.vtz = -1;
    gemm5<false, true><<<dim3(8, 16, 1), 256, 0, stream>>>(g2, 2048, 1024, 1024);
  }
}

// Round 11
// 235.750 us; speedup vs baseline: 1.5902x; 1.5902x over previous
//
#include <hip/hip_runtime.h>

typedef unsigned short u16;
typedef unsigned int   u32;
typedef __bf16 bf16x8 __attribute__((ext_vector_type(8)));
typedef float  f32x4  __attribute__((ext_vector_type(4)));

__device__ __forceinline__ float b2f(u16 s) { return __uint_as_float(((u32)s) << 16); }
__device__ __forceinline__ u16 f2b(float f) {
  u32 x = __float_as_uint(f);
  return (u16)((x + 0x7FFFu + ((x >> 16) & 1u)) >> 16);  // RNE, finite inputs only
}

#if __has_builtin(__builtin_amdgcn_exp2f)
#define EXP2(x) __builtin_amdgcn_exp2f(x)
#else
#define EXP2(x) exp2f(x)
#endif

// DPP 16-lane rotate-reduce (VALU pipe, no LDS) — row_ror:8/4/2/1
template <int C>
__device__ __forceinline__ u32 dppu(u32 s) {
  return (u32)__builtin_amdgcn_update_dpp((int)s, (int)s, C, 0xF, 0xF, false);
}
__device__ __forceinline__ float red_sum16(float x) {
  x += __uint_as_float(dppu<0x128>(__float_as_uint(x)));
  x += __uint_as_float(dppu<0x124>(__float_as_uint(x)));
  x += __uint_as_float(dppu<0x122>(__float_as_uint(x)));
  x += __uint_as_float(dppu<0x121>(__float_as_uint(x)));
  return x;
}

union U16x8 { uint4 u; u16 s[8]; };

__device__ __forceinline__ uint4 cvt8(const float4 a, const float4 b) {
  U16x8 r;
  r.s[0] = f2b(a.x); r.s[1] = f2b(a.y); r.s[2] = f2b(a.z); r.s[3] = f2b(a.w);
  r.s[4] = f2b(b.x); r.s[5] = f2b(b.y); r.s[6] = f2b(b.z); r.s[7] = f2b(b.w);
  return r.u;
}

// async global->LDS, 16B per lane. LDS dest is wave-uniform base + lane*16.
typedef __attribute__((address_space(3))) u32 lds_u32;
typedef const __attribute__((address_space(1))) u32 glb_u32;
__device__ __forceinline__ void gld16(const u16* gp, u16* lp) {
  __builtin_amdgcn_global_load_lds((glb_u32*)gp, (lds_u32*)lp, 16, 0, 0);
}

// ---------------------------------------------------------------------------
// f32 -> bf16 bulk convert (8 tensors in one launch; blockIdx.y = tensor id)
// ---------------------------------------------------------------------------
struct CvtArgs { const float* s[8]; u16* d[8]; int n[8]; };

__global__ __launch_bounds__(256) void cvt_bf16(CvtArgs c) {
  const int t = blockIdx.y;
  const int i = (blockIdx.x * 256 + threadIdx.x) * 8;
  if (i >= c.n[t]) return;
  const float4 a = *(const float4*)(c.s[t] + i);
  const float4 b = *(const float4*)(c.s[t] + i + 4);
  *(uint4*)(c.d[t] + i) = cvt8(a, b);
}

// ---------------------------------------------------------------------------
// m97-style bf16 GEMM: C[z] = A[z] (MxK bf16) @ W[z]^T (NxK bf16) + bias (f32)
// BM x BN block tile (BM,BN in {64,128}), BK=64, 4 waves as 2x2.
// ---------------------------------------------------------------------------
struct GemmBArgs { const u16* A[5]; const u16* W[5]; const float* Bi[5]; void* C[5]; int vtz; };

template <int BM, int BN, bool OUT_F32>
__global__ __launch_bounds__(256) void gemm_lds(GemmBArgs g, int M, int N, int K) {
  const int z = blockIdx.z;
  const u16* __restrict__ A = g.A[z];
  const u16* __restrict__ W = g.W[z];
  const float* __restrict__ Bi = g.Bi[z];

  const int m0 = blockIdx.y * BM, n0 = blockIdx.x * BN;
  const int tid = threadIdx.x, wv = tid >> 6, lane = tid & 63;
  const int wm = wv >> 1, wn = wv & 1;
  const int lr = lane & 15, lq = lane >> 4;
  constexpr int MT = BM / 32;
  constexpr int NT = BN / 32;

  __shared__ u16 As[BM * 64];
  __shared__ u16 Ws[BN * 64];

  const f32x4 vzero = {0.f, 0.f, 0.f, 0.f};
  f32x4 acc[MT][NT];
#pragma unroll
  for (int i = 0; i < MT; ++i)
#pragma unroll
    for (int j = 0; j < NT; ++j) acc[i][j] = vzero;

  const int srow = lane >> 3;                 // 0..7
  const int sc   = (lane & 7) ^ srow;         // swizzled 16B chunk index

  for (int kb = 0; kb < K; kb += 64) {
    __syncthreads();
#pragma unroll
    for (int t = 0; t < MT; ++t) {
      const u16* gp = A + (size_t)(m0 + t * 32 + wv * 8 + srow) * K + kb + sc * 8;
      gld16(gp, As + (t * 32 + wv * 8) * 64 + lane * 8);
    }
#pragma unroll
    for (int t = 0; t < NT; ++t) {
      const u16* gp = W + (size_t)(n0 + t * 32 + wv * 8 + srow) * K + kb + sc * 8;
      gld16(gp, Ws + (t * 32 + wv * 8) * 64 + lane * 8);
    }
    __syncthreads();
#pragma unroll
    for (int kk = 0; kk < 2; ++kk) {
      bf16x8 af[MT], bw[NT];
#pragma unroll
      for (int mt = 0; mt < MT; ++mt) {
        const int row = wm * (BM / 2) + mt * 16 + lr;
        af[mt] = *(const bf16x8*)&As[row * 64 + (((kk << 2) | lq) ^ (row & 7)) * 8];
      }
#pragma unroll
      for (int nt = 0; nt < NT; ++nt) {
        const int row = wn * (BN / 2) + nt * 16 + lr;
        bw[nt] = *(const bf16x8*)&Ws[row * 64 + (((kk << 2) | lq) ^ (row & 7)) * 8];
      }
#pragma unroll
      for (int mt = 0; mt < MT; ++mt)
#pragma unroll
        for (int nt = 0; nt < NT; ++nt)
          acc[mt][nt] = __builtin_amdgcn_mfma_f32_16x16x32_bf16(af[mt], bw[nt], acc[mt][nt], 0, 0, 0);
    }
  }

#pragma unroll
  for (int mt = 0; mt < MT; ++mt) {
#pragma unroll
    for (int nt = 0; nt < NT; ++nt) {
      const int col = n0 + wn * (BN / 2) + nt * 16 + lr;
      const float bia = Bi[col];
      const int row0 = m0 + wm * (BM / 2) + mt * 16 + lq * 4;
      if (OUT_F32) {
#pragma unroll
        for (int r = 0; r < 4; ++r)
          ((float*)g.C[z])[(size_t)(row0 + r) * N + col] = acc[mt][nt][r] + bia;
      } else if (z == g.vtz) {
        ushort4 pk;
        pk.x = f2b(acc[mt][nt][0] + bia); pk.y = f2b(acc[mt][nt][1] + bia);
        pk.z = f2b(acc[mt][nt][2] + bia); pk.w = f2b(acc[mt][nt][3] + bia);
        const int bb = row0 >> 10, s0 = row0 & 1023;
        *(ushort4*)((u16*)g.C[z] + ((size_t)bb << 20) + ((size_t)col << 10) + s0) = pk;
      } else {
#pragma unroll
        for (int r = 0; r < 4; ++r)
          ((u16*)g.C[z])[(size_t)(row0 + r) * N + col] = f2b(acc[mt][nt][r] + bia);
      }
    }
  }
}

// ---------------------------------------------------------------------------
// Fallback GEMM (ws too small for pre-convert): f32 stage-convert, proven R2.
// ---------------------------------------------------------------------------
struct GemmArgs { const void* A[5]; const float* W[5]; const float* Bi[5]; void* C[5]; int vtz; };

template <bool A_F32, bool OUT_F32>
__global__ __launch_bounds__(256) void gemm5(GemmArgs g, int M, int N, int K) {
  const int z = blockIdx.z;
  const float* __restrict__ Wf = g.W[z];
  const float* __restrict__ Bi = g.Bi[z];

  const int m0 = blockIdx.y * 128, n0 = blockIdx.x * 128;
  const int tid = threadIdx.x;
  const int wv = tid >> 6, lane = tid & 63;
  const int wm = wv >> 1, wn = wv & 1;
  const int lr = lane & 15, lq = lane >> 4;

  __shared__ alignas(16) u16 As[128][64];
  __shared__ alignas(16) u16 Ws[128][64];

  const f32x4 vzero = {0.f, 0.f, 0.f, 0.f};
  f32x4 acc[4][4];
#pragma unroll
  for (int i = 0; i < 4; ++i)
#pragma unroll
    for (int j = 0; j < 4; ++j) acc[i][j] = vzero;

  const int srow = tid >> 1;
  const int sc0  = (tid & 1) * 32;
  const float* pw = Wf + (size_t)(n0 + srow) * K + sc0;
  const float* paf = A_F32 ? ((const float*)g.A[z] + (size_t)(m0 + srow) * K + sc0) : nullptr;
  const u16*   pab = A_F32 ? nullptr : ((const u16*)g.A[z] + (size_t)(m0 + srow) * K + sc0);

  for (int k0 = 0; k0 < K; k0 += 64) {
#pragma unroll
    for (int u_ = 0; u_ < 4; ++u_) {
      const float4 w0 = *(const float4*)(pw + k0 + u_ * 8);
      const float4 w1 = *(const float4*)(pw + k0 + u_ * 8 + 4);
      *(uint4*)&Ws[srow][sc0 + u_ * 8] = cvt8(w0, w1);
      if (A_F32) {
        const float4 a0 = *(const float4*)(paf + k0 + u_ * 8);
        const float4 a1 = *(const float4*)(paf + k0 + u_ * 8 + 4);
        *(uint4*)&As[srow][sc0 + u_ * 8] = cvt8(a0, a1);
      } else {
        *(uint4*)&As[srow][sc0 + u_ * 8] = *(const uint4*)(pab + k0 + u_ * 8);
      }
    }
    __syncthreads();
#pragma unroll
    for (int kk = 0; kk < 2; ++kk) {
      bf16x8 af[4], bfr[4];
#pragma unroll
      for (int mt = 0; mt < 4; ++mt)
        af[mt] = *(const bf16x8*)&As[wm * 64 + mt * 16 + lr][kk * 32 + lq * 8];
#pragma unroll
      for (int nt = 0; nt < 4; ++nt)
        bfr[nt] = *(const bf16x8*)&Ws[wn * 64 + nt * 16 + lr][kk * 32 + lq * 8];
#pragma unroll
      for (int mt = 0; mt < 4; ++mt)
#pragma unroll
        for (int nt = 0; nt < 4; ++nt)
          acc[mt][nt] = __builtin_amdgcn_mfma_f32_16x16x32_bf16(af[mt], bfr[nt], acc[mt][nt], 0, 0, 0);
    }
    __syncthreads();
  }

#pragma unroll
  for (int mt = 0; mt < 4; ++mt) {
#pragma unroll
    for (int nt = 0; nt < 4; ++nt) {
      const int col = n0 + wn * 64 + nt * 16 + lr;
      const float bia = Bi[col];
      const int row0 = m0 + wm * 64 + mt * 16 + lq * 4;
      if (OUT_F32) {
#pragma unroll
        for (int r = 0; r < 4; ++r)
          ((float*)g.C[z])[(size_t)(row0 + r) * N + col] = acc[mt][nt][r] + bia;
      } else if (z == g.vtz) {
        ushort4 pk;
        pk.x = f2b(acc[mt][nt][0] + bia); pk.y = f2b(acc[mt][nt][1] + bia);
        pk.z = f2b(acc[mt][nt][2] + bia); pk.w = f2b(acc[mt][nt][3] + bia);
        const int bb = row0 >> 10, s0 = row0 & 1023;
        *(ushort4*)((u16*)g.C[z] + ((size_t)bb << 20) + ((size_t)col << 10) + s0) = pk;
      } else {
#pragma unroll
        for (int r = 0; r < 4; ++r)
          ((u16*)g.C[z])[(size_t)(row0 + r) * N + col] = f2b(acc[mt][nt][r] + bia);
      }
    }
  }
}

// ---------------------------------------------------------------------------
// Barrier-free per-wave disentangled attention, v8.
// = R9's no-max softmax + R7's NON-aliased LDS layout (separate Pb) with
// ZERO asm memory barriers: the R9 barriers pinned global-load prefetch
// depth to 0 (every iter ate a full L2 round trip). Separate Pb removes the
// alias that required them; R7 ran correct in this layout without barriers.
// launch_bounds(256,2) — NO tighter cap (R5 and R10 both spilled massively).
// ---------------------------------------------------------------------------
__global__ __launch_bounds__(256, 2) void attn_wave(
    const u16* __restrict__ q, const u16* __restrict__ k,
    const u16* __restrict__ vT, const u16* __restrict__ qr,
    const u16* __restrict__ kr, const int* __restrict__ pmask,
    u16* __restrict__ ao) {
  constexpr int S = 1024, Dm = 1024;
  constexpr int GP = 37;           // f32 stride of G1f/G2f rows
  constexpr int PBP = 36;          // u16 stride of Pb rows
  constexpr int WLDS = 11776;      // per-wave LDS: 4736 + 4736 + 2304

  __shared__ alignas(16) char smem[4 * WLDS];

  const int bx = blockIdx.x;
  const int bh = bx & 31, it = bx >> 5;   // bh-inner => (b,h) stays on one XCD
  const int bb = bh >> 4, h = bh & 15;
  const int i0 = it * 32;

  const int tid = threadIdx.x;
  const int wv = tid >> 6, lane = tid & 63;
  const int lq = lane >> 4, lr = lane & 15;

  char* wbase = smem + wv * WLDS;
  float* G1f = (float*)wbase;              // 1184 f32: [2 pad][32 rows x 37]
  float* G2f = (float*)(wbase + 4736);     // same layout
  u16*   Pb  = (u16*)(wbase + 9472);       // [32][36] — separate, no alias

  const u16* qb  = q  + ((size_t)bb << 20) + h * 64;
  const u16* kb  = k  + ((size_t)bb << 20) + h * 64;
  const u16* qrb = qr + ((size_t)bb << 20) + h * 64;
  const u16* krb = kr + ((size_t)bb << 20) + h * 64;
  const u16* vtb = vT + ((size_t)bb << 20) + ((size_t)h << 16);
  const int* pmb = pmask + ((size_t)bb << 10);

  const float kscale = 1.44269504088896f / 13.856406460551018f;  // log2e/sqrt(192)

  // cached Q A-frags: rows i0 + mt*16 + lr, k-chunks kk*32 + lq*8
  bf16x8 qf[2][2];
#pragma unroll
  for (int mt = 0; mt < 2; ++mt)
#pragma unroll
    for (int kk = 0; kk < 2; ++kk)
      qf[mt][kk] = *(const bf16x8*)(qb + (size_t)(i0 + mt * 16 + lr) * Dm + kk * 32 + lq * 8);

  const f32x4 vzero = {0.f, 0.f, 0.f, 0.f};
  f32x4 o[2][4];
#pragma unroll
  for (int mt = 0; mt < 2; ++mt)
#pragma unroll
    for (int nd = 0; nd < 4; ++nd) o[mt][nd] = vzero;
  float lst[2][4];  // per-lane partial sum of P (over this lane's b columns)
#pragma unroll
  for (int mt = 0; mt < 2; ++mt)
#pragma unroll
    for (int r = 0; r < 4; ++r) lst[mt][r] = 0.f;

#pragma unroll 1
  for (int t8 = 0; t8 < 8; ++t8) {
    const int j0 = (wv + t8 * 4) * 32;
    const int pb_ = i0 - j0 + 481;  // window row t -> global row clamp(pb_ + t)

    // ---- K, V fragments (direct from global) ----
    bf16x8 kf[2][2], vf[4];
#pragma unroll
    for (int nt = 0; nt < 2; ++nt) {
      const u16* kp = kb + (size_t)(j0 + nt * 16 + lr) * Dm + lq * 8;
      kf[nt][0] = *(const bf16x8*)kp;
      kf[nt][1] = *(const bf16x8*)(kp + 32);
    }
#pragma unroll
    for (int n4 = 0; n4 < 4; ++n4)
      vf[n4] = *(const bf16x8*)(vtb + (size_t)(n4 * 16 + lr) * S + j0 + lq * 8);
    const int mv0 = pmb[j0 + lr], mv1 = pmb[j0 + 16 + lr];

    // ---- c2c into registers (C-layout) ----
    f32x4 cc[2][2];
#pragma unroll
    for (int mt = 0; mt < 2; ++mt)
#pragma unroll
      for (int nt = 0; nt < 2; ++nt) {
        f32x4 a = vzero;
        a = __builtin_amdgcn_mfma_f32_16x16x32_bf16(qf[mt][0], kf[nt][0], a, 0, 0, 0);
        a = __builtin_amdgcn_mfma_f32_16x16x32_bf16(qf[mt][1], kf[nt][1], a, 0, 0, 0);
        cc[mt][nt] = a;
      }

    // ---- G1 = Q@KRw^T and G2' = K@QRw^T, per-n4 slices, redirect stores ----
#pragma unroll
    for (int n4 = 0; n4 < 4; ++n4) {
      int p = pb_ + n4 * 16 + lr;
      p = p < 0 ? 0 : (p > 1023 ? 1023 : p);
      const u16* kp = krb + (size_t)p * Dm + lq * 8;
      const u16* qp = qrb + (size_t)p * Dm + lq * 8;
      const bf16x8 kr0 = *(const bf16x8*)kp;
      const bf16x8 kr1 = *(const bf16x8*)(kp + 32);
      const bf16x8 qr0 = *(const bf16x8*)qp;
      const bf16x8 qr1 = *(const bf16x8*)(qp + 32);
      const int tb = n4 * 16 + lr;
#pragma unroll
      for (int mt = 0; mt < 2; ++mt) {
        f32x4 a = vzero;
        a = __builtin_amdgcn_mfma_f32_16x16x32_bf16(qf[mt][0], kr0, a, 0, 0, 0);
        a = __builtin_amdgcn_mfma_f32_16x16x32_bf16(qf[mt][1], kr1, a, 0, 0, 0);
#pragma unroll
        for (int r = 0; r < 4; ++r) {
          const int arow = mt * 16 + lq * 4 + r;
          int u = tb - arow;                       // valid band: [0,32)
          u = u < -2 ? -2 : (u > 34 ? 34 : u);     // invalid -> row padding
          G1f[2 + arow * GP + u] = a[r];
        }
      }
#pragma unroll
      for (int mt = 0; mt < 2; ++mt) {
        f32x4 g = vzero;
        g = __builtin_amdgcn_mfma_f32_16x16x32_bf16(kf[mt][0], qr0, g, 0, 0, 0);
        g = __builtin_amdgcn_mfma_f32_16x16x32_bf16(kf[mt][1], qr1, g, 0, 0, 0);
#pragma unroll
        for (int r = 0; r < 4; ++r) {
          const int brow = mt * 16 + lq * 4 + r;
          int u = tb + brow - 31;                  // valid band: [0,32)
          u = u < -2 ? -2 : (u > 34 ? 34 : u);
          G2f[2 + brow * GP + u] = g[r];
        }
      }
    }

    // ---- no-max softmax: P = exp2(s), l += sum(P) per-lane, pack to Pb ----
#pragma unroll
    for (int mt = 0; mt < 2; ++mt) {
#pragma unroll
      for (int r = 0; r < 4; ++r) {
        const int a_ = mt * 16 + lq * 4 + r;
        float s0 = cc[mt][0][r] + G1f[2 + a_ * GP + 31 - lr] + G2f[2 + lr * GP + a_];
        float s1 = cc[mt][1][r] + G1f[2 + a_ * GP + 15 - lr] + G2f[2 + (16 + lr) * GP + a_];
        s0 = mv0 ? -1e30f : s0 * kscale;
        s1 = mv1 ? -1e30f : s1 * kscale;
        const float p0 = EXP2(s0);
        const float p1 = EXP2(s1);
        lst[mt][r] += p0 + p1;
        Pb[a_ * PBP + lr]      = f2b(p0);
        Pb[a_ * PBP + 16 + lr] = f2b(p1);
      }
    }

    // ---- PV: read P A-frags, accumulate (no rescale — unnormalized) ----
#pragma unroll
    for (int mt = 0; mt < 2; ++mt) {
      union { uint2 u2[2]; bf16x8 v; } pr;
      const u16* prow = Pb + (mt * 16 + lr) * PBP + lq * 8;
      pr.u2[0] = *(const uint2*)prow;
      pr.u2[1] = *(const uint2*)(prow + 4);
#pragma unroll
      for (int nd = 0; nd < 4; ++nd)
        o[mt][nd] = __builtin_amdgcn_mfma_f32_16x16x32_bf16(pr.v, vf[nd], o[mt][nd], 0, 0, 0);
    }
  }

  // ---- dump per-wave state, merge 4 ways, write ao ----
  {
    float* Orm = (float*)wbase;            // [32][64]
    float* llw = (float*)(wbase + 8192);   // [32]
#pragma unroll
    for (int mt = 0; mt < 2; ++mt)
#pragma unroll
      for (int nd = 0; nd < 4; ++nd)
#pragma unroll
        for (int r = 0; r < 4; ++r)
          Orm[(mt * 16 + lq * 4 + r) * 64 + nd * 16 + lr] = o[mt][nd][r];
#pragma unroll
    for (int mt = 0; mt < 2; ++mt)
#pragma unroll
      for (int r = 0; r < 4; ++r) {
        const float rl = red_sum16(lst[mt][r]);   // row-total l (once, not per iter)
        if (lr == 0) llw[mt * 16 + lq * 4 + r] = rl;
      }
  }
  __syncthreads();
  {
    const int a_ = tid >> 3, d0 = (tid & 7) * 8;
    float L = 0.f, acc[8];
#pragma unroll
    for (int d = 0; d < 8; ++d) acc[d] = 0.f;
#pragma unroll
    for (int w = 0; w < 4; ++w) {
      const char* wb = smem + w * WLDS;
      L += *(const float*)(wb + 8192 + a_ * 4);
      const float* Ow = (const float*)wb + a_ * 64 + d0;
#pragma unroll
      for (int d = 0; d < 8; ++d) acc[d] += Ow[d];
    }
    const float inv = 1.f / L;
    U16x8 pk;
#pragma unroll
    for (int d = 0; d < 8; ++d) pk.s[d] = f2b(acc[d] * inv);
    *(uint4*)(ao + ((size_t)((bb << 10) + i0 + a_) << 10) + (h << 6) + d0) = pk.u;
  }
}

// ---------------------------------------------------------------------------
extern "C" void kernel_launch(void* const* d_in, const int* in_sizes, int n_in,
                              void* d_out, int out_size, void* d_ws, size_t ws_size,
                              hipStream_t stream) {
  const float* x   = (const float*)d_in[0];
  const float* rpe = (const float*)d_in[1];
  const int*   pm  = (const int*)d_in[2];
  const float* Wq  = (const float*)d_in[3];  const float* bq  = (const float*)d_in[4];
  const float* Wk  = (const float*)d_in[5];  const float* bk  = (const float*)d_in[6];
  const float* Wv  = (const float*)d_in[7];  const float* bv  = (const float*)d_in[8];
  const float* Wqr = (const float*)d_in[9];  const float* bqr = (const float*)d_in[10];
  const float* Wkr = (const float*)d_in[11]; const float* bkr = (const float*)d_in[12];
  const float* Wc  = (const float*)d_in[13]; const float* bc  = (const float*)d_in[14];

  const size_t NE = (size_t)2 * 1024 * 1024;  // B*S*D elements
  const size_t WE = (size_t)1024 * 1024;      // D*D elements
  u16* ws = (u16*)d_ws;

  if (ws_size >= (10 * NE + 6 * WE) * sizeof(u16)) {
    u16* q   = ws;          u16* k   = ws + NE;     u16* vT  = ws + 2 * NE;
    u16* qr  = ws + 3 * NE; u16* kr  = ws + 4 * NE;
    u16* xb  = ws + 5 * NE;
    u16* ao  = ws + 5 * NE;  // same slot: xb dead once proj GEMM finishes
    u16* rpb = ws + 6 * NE;
    u16* wb  = ws + 7 * NE;
    u16* Wqb = wb;           u16* Wkb = wb + WE;     u16* Wvb = wb + 2 * WE;
    u16* Wqrb= wb + 3 * WE;  u16* Wkrb= wb + 4 * WE; u16* Wcb = wb + 5 * WE;

    CvtArgs c;
    c.s[0] = x;   c.d[0] = xb;   c.n[0] = (int)NE;
    c.s[1] = rpe; c.d[1] = rpb;  c.n[1] = (int)NE;
    c.s[2] = Wq;  c.d[2] = Wqb;  c.n[2] = (int)WE;
    c.s[3] = Wk;  c.d[3] = Wkb;  c.n[3] = (int)WE;
    c.s[4] = Wv;  c.d[4] = Wvb;  c.n[4] = (int)WE;
    c.s[5] = Wqr; c.d[5] = Wqrb; c.n[5] = (int)WE;
    c.s[6] = Wkr; c.d[6] = Wkrb; c.n[6] = (int)WE;
    c.s[7] = Wc;  c.d[7] = Wcb;  c.n[7] = (int)WE;
    cvt_bf16<<<dim3(1024, 8), 256, 0, stream>>>(c);

    GemmBArgs g;
    g.A[0] = xb;  g.W[0] = Wqb;  g.Bi[0] = bq;  g.C[0] = q;
    g.A[1] = xb;  g.W[1] = Wkb;  g.Bi[1] = bk;  g.C[1] = k;
    g.A[2] = xb;  g.W[2] = Wvb;  g.Bi[2] = bv;  g.C[2] = vT;
    g.A[3] = rpb; g.W[3] = Wqrb; g.Bi[3] = bqr; g.C[3] = qr;
    g.A[4] = rpb; g.W[4] = Wkrb; g.Bi[4] = bkr; g.C[4] = kr;
    g.vtz = 2;
    gemm_lds<128, 128, false><<<dim3(8, 16, 5), 256, 0, stream>>>(g, 2048, 1024, 1024);

    attn_wave<<<dim3(1024), 256, 0, stream>>>(q, k, vT, qr, kr, pm, ao);

    GemmBArgs g2;
    for (int i = 0; i < 5; ++i) { g2.A[i] = ao; g2.W[i] = Wcb; g2.Bi[i] = bc; g2.C[i] = d_out; }
    g2.vtz = -1;
    gemm_lds<64, 64, true><<<dim3(16, 32, 1), 256, 0, stream>>>(g2, 2048, 1024, 1024);
  } else {
    if (ws_size < 6 * NE * sizeof(u16)) return;
    u16* q  = ws;          u16* k  = ws + NE;     u16* vT = ws + 2 * NE;
    u16* qr = ws + 3 * NE; u16* kr = ws + 4 * NE; u16* ao = ws + 5 * NE;

    GemmArgs g;
    g.A[0] = x;   g.W[0] = Wq;  g.Bi[0] = bq;  g.C[0] = q;
    g.A[1] = x;   g.W[1] = Wk;  g.Bi[1] = bk;  g.C[1] = k;
    g.A[2] = x;   g.W[2] = Wv;  g.Bi[2] = bv;  g.C[2] = vT;
    g.A[3] = rpe; g.W[3] = Wqr; g.Bi[3] = bqr; g.C[3] = qr;
    g.A[4] = rpe; g.W[4] = Wkr; g.Bi[4] = bkr; g.C[4] = kr;
    g.vtz = 2;
    gemm5<true, false><<<dim3(8, 16, 5), 256, 0, stream>>>(g, 2048, 1024, 1024);

    attn_wave<<<dim3(1024), 256, 0, stream>>>(q, k, vT, qr, kr, pm, ao);

    GemmArgs g2;
    for (int i = 0; i < 5; ++i) { g2.A[i] = ao; g2.W[i] = Wc; g2.Bi[i] = bc; g2.C[i] = d_out; }
    g2.vtz = -1;
    gemm5<false, true><<<dim3(8, 16, 1), 256, 0, stream>>>(g2, 2048, 1024, 1024);
  }
}

// Round 12
// 232.256 us; speedup vs baseline: 1.6141x; 1.0150x over previous
//
#include <hip/hip_runtime.h>

typedef unsigned short u16;
typedef unsigned int   u32;
typedef __bf16 bf16x8 __attribute__((ext_vector_type(8)));
typedef float  f32x4  __attribute__((ext_vector_type(4)));

__device__ __forceinline__ float b2f(u16 s) { return __uint_as_float(((u32)s) << 16); }
__device__ __forceinline__ u16 f2b(float f) {
  u32 x = __float_as_uint(f);
  return (u16)((x + 0x7FFFu + ((x >> 16) & 1u)) >> 16);  // RNE, finite inputs only
}

#if __has_builtin(__builtin_amdgcn_exp2f)
#define EXP2(x) __builtin_amdgcn_exp2f(x)
#else
#define EXP2(x) exp2f(x)
#endif

// DPP 16-lane rotate-reduce (VALU pipe, no LDS) — row_ror:8/4/2/1
template <int C>
__device__ __forceinline__ u32 dppu(u32 s) {
  return (u32)__builtin_amdgcn_update_dpp((int)s, (int)s, C, 0xF, 0xF, false);
}
__device__ __forceinline__ float red_sum16(float x) {
  x += __uint_as_float(dppu<0x128>(__float_as_uint(x)));
  x += __uint_as_float(dppu<0x124>(__float_as_uint(x)));
  x += __uint_as_float(dppu<0x122>(__float_as_uint(x)));
  x += __uint_as_float(dppu<0x121>(__float_as_uint(x)));
  return x;
}

union U16x8 { uint4 u; u16 s[8]; };

__device__ __forceinline__ uint4 cvt8(const float4 a, const float4 b) {
  U16x8 r;
  r.s[0] = f2b(a.x); r.s[1] = f2b(a.y); r.s[2] = f2b(a.z); r.s[3] = f2b(a.w);
  r.s[4] = f2b(b.x); r.s[5] = f2b(b.y); r.s[6] = f2b(b.z); r.s[7] = f2b(b.w);
  return r.u;
}

// async global->LDS, 16B per lane. LDS dest is wave-uniform base + lane*16.
typedef __attribute__((address_space(3))) u32 lds_u32;
typedef const __attribute__((address_space(1))) u32 glb_u32;
__device__ __forceinline__ void gld16(const u16* gp, u16* lp) {
  __builtin_amdgcn_global_load_lds((glb_u32*)gp, (lds_u32*)lp, 16, 0, 0);
}

// ---------------------------------------------------------------------------
// f32 -> bf16 bulk convert (8 tensors in one launch; blockIdx.y = tensor id)
// ---------------------------------------------------------------------------
struct CvtArgs { const float* s[8]; u16* d[8]; int n[8]; };

__global__ __launch_bounds__(256) void cvt_bf16(CvtArgs c) {
  const int t = blockIdx.y;
  const int i = (blockIdx.x * 256 + threadIdx.x) * 8;
  if (i >= c.n[t]) return;
  const float4 a = *(const float4*)(c.s[t] + i);
  const float4 b = *(const float4*)(c.s[t] + i + 4);
  *(uint4*)(c.d[t] + i) = cvt8(a, b);
}

// ---------------------------------------------------------------------------
// m97-style bf16 GEMM: C[z] = A[z] (MxK bf16) @ W[z]^T (NxK bf16) + bias (f32)
// BM x BN block tile (BM,BN in {64,128}), BK=64, 4 waves as 2x2.
// ---------------------------------------------------------------------------
struct GemmBArgs { const u16* A[5]; const u16* W[5]; const float* Bi[5]; void* C[5]; int vtz; };

template <int BM, int BN, bool OUT_F32>
__global__ __launch_bounds__(256) void gemm_lds(GemmBArgs g, int M, int N, int K) {
  const int z = blockIdx.z;
  const u16* __restrict__ A = g.A[z];
  const u16* __restrict__ W = g.W[z];
  const float* __restrict__ Bi = g.Bi[z];

  const int m0 = blockIdx.y * BM, n0 = blockIdx.x * BN;
  const int tid = threadIdx.x, wv = tid >> 6, lane = tid & 63;
  const int wm = wv >> 1, wn = wv & 1;
  const int lr = lane & 15, lq = lane >> 4;
  constexpr int MT = BM / 32;
  constexpr int NT = BN / 32;

  __shared__ u16 As[BM * 64];
  __shared__ u16 Ws[BN * 64];

  const f32x4 vzero = {0.f, 0.f, 0.f, 0.f};
  f32x4 acc[MT][NT];
#pragma unroll
  for (int i = 0; i < MT; ++i)
#pragma unroll
    for (int j = 0; j < NT; ++j) acc[i][j] = vzero;

  const int srow = lane >> 3;                 // 0..7
  const int sc   = (lane & 7) ^ srow;         // swizzled 16B chunk index

  for (int kb = 0; kb < K; kb += 64) {
    __syncthreads();
#pragma unroll
    for (int t = 0; t < MT; ++t) {
      const u16* gp = A + (size_t)(m0 + t * 32 + wv * 8 + srow) * K + kb + sc * 8;
      gld16(gp, As + (t * 32 + wv * 8) * 64 + lane * 8);
    }
#pragma unroll
    for (int t = 0; t < NT; ++t) {
      const u16* gp = W + (size_t)(n0 + t * 32 + wv * 8 + srow) * K + kb + sc * 8;
      gld16(gp, Ws + (t * 32 + wv * 8) * 64 + lane * 8);
    }
    __syncthreads();
#pragma unroll
    for (int kk = 0; kk < 2; ++kk) {
      bf16x8 af[MT], bw[NT];
#pragma unroll
      for (int mt = 0; mt < MT; ++mt) {
        const int row = wm * (BM / 2) + mt * 16 + lr;
        af[mt] = *(const bf16x8*)&As[row * 64 + (((kk << 2) | lq) ^ (row & 7)) * 8];
      }
#pragma unroll
      for (int nt = 0; nt < NT; ++nt) {
        const int row = wn * (BN / 2) + nt * 16 + lr;
        bw[nt] = *(const bf16x8*)&Ws[row * 64 + (((kk << 2) | lq) ^ (row & 7)) * 8];
      }
#pragma unroll
      for (int mt = 0; mt < MT; ++mt)
#pragma unroll
        for (int nt = 0; nt < NT; ++nt)
          acc[mt][nt] = __builtin_amdgcn_mfma_f32_16x16x32_bf16(af[mt], bw[nt], acc[mt][nt], 0, 0, 0);
    }
  }

#pragma unroll
  for (int mt = 0; mt < MT; ++mt) {
#pragma unroll
    for (int nt = 0; nt < NT; ++nt) {
      const int col = n0 + wn * (BN / 2) + nt * 16 + lr;
      const float bia = Bi[col];
      const int row0 = m0 + wm * (BM / 2) + mt * 16 + lq * 4;
      if (OUT_F32) {
#pragma unroll
        for (int r = 0; r < 4; ++r)
          ((float*)g.C[z])[(size_t)(row0 + r) * N + col] = acc[mt][nt][r] + bia;
      } else if (z == g.vtz) {
        ushort4 pk;
        pk.x = f2b(acc[mt][nt][0] + bia); pk.y = f2b(acc[mt][nt][1] + bia);
        pk.z = f2b(acc[mt][nt][2] + bia); pk.w = f2b(acc[mt][nt][3] + bia);
        const int bb = row0 >> 10, s0 = row0 & 1023;
        *(ushort4*)((u16*)g.C[z] + ((size_t)bb << 20) + ((size_t)col << 10) + s0) = pk;
      } else {
#pragma unroll
        for (int r = 0; r < 4; ++r)
          ((u16*)g.C[z])[(size_t)(row0 + r) * N + col] = f2b(acc[mt][nt][r] + bia);
      }
    }
  }
}

// ---------------------------------------------------------------------------
// Fallback GEMM (ws too small for pre-convert): f32 stage-convert, proven R2.
// ---------------------------------------------------------------------------
struct GemmArgs { const void* A[5]; const float* W[5]; const float* Bi[5]; void* C[5]; int vtz; };

template <bool A_F32, bool OUT_F32>
__global__ __launch_bounds__(256) void gemm5(GemmArgs g, int M, int N, int K) {
  const int z = blockIdx.z;
  const float* __restrict__ Wf = g.W[z];
  const float* __restrict__ Bi = g.Bi[z];

  const int m0 = blockIdx.y * 128, n0 = blockIdx.x * 128;
  const int tid = threadIdx.x;
  const int wv = tid >> 6, lane = tid & 63;
  const int wm = wv >> 1, wn = wv & 1;
  const int lr = lane & 15, lq = lane >> 4;

  __shared__ alignas(16) u16 As[128][64];
  __shared__ alignas(16) u16 Ws[128][64];

  const f32x4 vzero = {0.f, 0.f, 0.f, 0.f};
  f32x4 acc[4][4];
#pragma unroll
  for (int i = 0; i < 4; ++i)
#pragma unroll
    for (int j = 0; j < 4; ++j) acc[i][j] = vzero;

  const int srow = tid >> 1;
  const int sc0  = (tid & 1) * 32;
  const float* pw = Wf + (size_t)(n0 + srow) * K + sc0;
  const float* paf = A_F32 ? ((const float*)g.A[z] + (size_t)(m0 + srow) * K + sc0) : nullptr;
  const u16*   pab = A_F32 ? nullptr : ((const u16*)g.A[z] + (size_t)(m0 + srow) * K + sc0);

  for (int k0 = 0; k0 < K; k0 += 64) {
#pragma unroll
    for (int u_ = 0; u_ < 4; ++u_) {
      const float4 w0 = *(const float4*)(pw + k0 + u_ * 8);
      const float4 w1 = *(const float4*)(pw + k0 + u_ * 8 + 4);
      *(uint4*)&Ws[srow][sc0 + u_ * 8] = cvt8(w0, w1);
      if (A_F32) {
        const float4 a0 = *(const float4*)(paf + k0 + u_ * 8);
        const float4 a1 = *(const float4*)(paf + k0 + u_ * 8 + 4);
        *(uint4*)&As[srow][sc0 + u_ * 8] = cvt8(a0, a1);
      } else {
        *(uint4*)&As[srow][sc0 + u_ * 8] = *(const uint4*)(pab + k0 + u_ * 8);
      }
    }
    __syncthreads();
#pragma unroll
    for (int kk = 0; kk < 2; ++kk) {
      bf16x8 af[4], bfr[4];
#pragma unroll
      for (int mt = 0; mt < 4; ++mt)
        af[mt] = *(const bf16x8*)&As[wm * 64 + mt * 16 + lr][kk * 32 + lq * 8];
#pragma unroll
      for (int nt = 0; nt < 4; ++nt)
        bfr[nt] = *(const bf16x8*)&Ws[wn * 64 + nt * 16 + lr][kk * 32 + lq * 8];
#pragma unroll
      for (int mt = 0; mt < 4; ++mt)
#pragma unroll
        for (int nt = 0; nt < 4; ++nt)
          acc[mt][nt] = __builtin_amdgcn_mfma_f32_16x16x32_bf16(af[mt], bfr[nt], acc[mt][nt], 0, 0, 0);
    }
    __syncthreads();
  }

#pragma unroll
  for (int mt = 0; mt < 4; ++mt) {
#pragma unroll
    for (int nt = 0; nt < 4; ++nt) {
      const int col = n0 + wn * 64 + nt * 16 + lr;
      const float bia = Bi[col];
      const int row0 = m0 + wm * 64 + mt * 16 + lq * 4;
      if (OUT_F32) {
#pragma unroll
        for (int r = 0; r < 4; ++r)
          ((float*)g.C[z])[(size_t)(row0 + r) * N + col] = acc[mt][nt][r] + bia;
      } else if (z == g.vtz) {
        ushort4 pk;
        pk.x = f2b(acc[mt][nt][0] + bia); pk.y = f2b(acc[mt][nt][1] + bia);
        pk.z = f2b(acc[mt][nt][2] + bia); pk.w = f2b(acc[mt][nt][3] + bia);
        const int bb = row0 >> 10, s0 = row0 & 1023;
        *(ushort4*)((u16*)g.C[z] + ((size_t)bb << 20) + ((size_t)col << 10) + s0) = pk;
      } else {
#pragma unroll
        for (int r = 0; r < 4; ++r)
          ((u16*)g.C[z])[(size_t)(row0 + r) * N + col] = f2b(acc[mt][nt][r] + bia);
      }
    }
  }
}

// ---------------------------------------------------------------------------
// Barrier-free per-wave disentangled attention, v9.
// = R10's proven-correct body (aliased Pb, asm barriers, no-max softmax,
// DEFERRED vf loads) but with launch_bounds(256,2) — NO register cap.
// Theory: R11 measured 124 arch + 48 acc = 172 total regs, 2 over the
// 512/3=170 boundary for 3 waves/SIMD. Deferring vf (16 VGPRs) out of the
// G-phase live range should land total <=168 -> hardware grants 3 waves/SIMD
// with no cap and no spill. The asm barrier pins vf below the softmax so the
// scheduler cannot hoist it back into the peak.
// ---------------------------------------------------------------------------
__global__ __launch_bounds__(256, 2) void attn_wave(
    const u16* __restrict__ q, const u16* __restrict__ k,
    const u16* __restrict__ vT, const u16* __restrict__ qr,
    const u16* __restrict__ kr, const int* __restrict__ pmask,
    u16* __restrict__ ao) {
  constexpr int S = 1024, Dm = 1024;
  constexpr int GP = 37;           // f32 stride of G1f/G2f rows
  constexpr int PBP = 74;          // u16 stride of Pb rows (= one G1f row)
  constexpr int WLDS = 9472;       // per-wave LDS: 4736 (G1f+Pb alias) + 4736

  __shared__ alignas(16) char smem[4 * WLDS];

  const int bx = blockIdx.x;
  const int bh = bx & 31, it = bx >> 5;   // bh-inner => (b,h) stays on one XCD
  const int bb = bh >> 4, h = bh & 15;
  const int i0 = it * 32;

  const int tid = threadIdx.x;
  const int wv = tid >> 6, lane = tid & 63;
  const int lq = lane >> 4, lr = lane & 15;

  char* wbase = smem + wv * WLDS;
  float* G1f = (float*)wbase;              // 1184 f32: [2 pad][32 rows x 37]
  float* G2f = (float*)(wbase + 4736);     // same layout (never aliased)
  u16*   Pb  = (u16*)wbase;                // rows at 148B stride, bytes [0,64)

  const u16* qb  = q  + ((size_t)bb << 20) + h * 64;
  const u16* kb  = k  + ((size_t)bb << 20) + h * 64;
  const u16* qrb = qr + ((size_t)bb << 20) + h * 64;
  const u16* krb = kr + ((size_t)bb << 20) + h * 64;
  const u16* vtb = vT + ((size_t)bb << 20) + ((size_t)h << 16);
  const int* pmb = pmask + ((size_t)bb << 10);

  const float kscale = 1.44269504088896f / 13.856406460551018f;  // log2e/sqrt(192)

  // cached Q A-frags: rows i0 + mt*16 + lr, k-chunks kk*32 + lq*8
  bf16x8 qf[2][2];
#pragma unroll
  for (int mt = 0; mt < 2; ++mt)
#pragma unroll
    for (int kk = 0; kk < 2; ++kk)
      qf[mt][kk] = *(const bf16x8*)(qb + (size_t)(i0 + mt * 16 + lr) * Dm + kk * 32 + lq * 8);

  const f32x4 vzero = {0.f, 0.f, 0.f, 0.f};
  f32x4 o[2][4];
#pragma unroll
  for (int mt = 0; mt < 2; ++mt)
#pragma unroll
    for (int nd = 0; nd < 4; ++nd) o[mt][nd] = vzero;
  float lst[2][4];  // per-lane partial sum of P (over this lane's b columns)
#pragma unroll
  for (int mt = 0; mt < 2; ++mt)
#pragma unroll
    for (int r = 0; r < 4; ++r) lst[mt][r] = 0.f;

#pragma unroll 1
  for (int t8 = 0; t8 < 8; ++t8) {
    const int j0 = (wv + t8 * 4) * 32;
    const int pb_ = i0 - j0 + 481;  // window row t -> global row clamp(pb_ + t)

    // ---- K fragments (direct from global) ----
    bf16x8 kf[2][2];
#pragma unroll
    for (int nt = 0; nt < 2; ++nt) {
      const u16* kp = kb + (size_t)(j0 + nt * 16 + lr) * Dm + lq * 8;
      kf[nt][0] = *(const bf16x8*)kp;
      kf[nt][1] = *(const bf16x8*)(kp + 32);
    }
    const int mv0 = pmb[j0 + lr], mv1 = pmb[j0 + 16 + lr];

    // ---- c2c into registers (C-layout) ----
    f32x4 cc[2][2];
#pragma unroll
    for (int mt = 0; mt < 2; ++mt)
#pragma unroll
      for (int nt = 0; nt < 2; ++nt) {
        f32x4 a = vzero;
        a = __builtin_amdgcn_mfma_f32_16x16x32_bf16(qf[mt][0], kf[nt][0], a, 0, 0, 0);
        a = __builtin_amdgcn_mfma_f32_16x16x32_bf16(qf[mt][1], kf[nt][1], a, 0, 0, 0);
        cc[mt][nt] = a;
      }

    // ---- G1 = Q@KRw^T and G2' = K@QRw^T, per-n4 slices, redirect stores ----
#pragma unroll
    for (int n4 = 0; n4 < 4; ++n4) {
      int p = pb_ + n4 * 16 + lr;
      p = p < 0 ? 0 : (p > 1023 ? 1023 : p);
      const u16* kp = krb + (size_t)p * Dm + lq * 8;
      const u16* qp = qrb + (size_t)p * Dm + lq * 8;
      const bf16x8 kr0 = *(const bf16x8*)kp;
      const bf16x8 kr1 = *(const bf16x8*)(kp + 32);
      const bf16x8 qr0 = *(const bf16x8*)qp;
      const bf16x8 qr1 = *(const bf16x8*)(qp + 32);
      const int tb = n4 * 16 + lr;
#pragma unroll
      for (int mt = 0; mt < 2; ++mt) {
        f32x4 a = vzero;
        a = __builtin_amdgcn_mfma_f32_16x16x32_bf16(qf[mt][0], kr0, a, 0, 0, 0);
        a = __builtin_amdgcn_mfma_f32_16x16x32_bf16(qf[mt][1], kr1, a, 0, 0, 0);
#pragma unroll
        for (int r = 0; r < 4; ++r) {
          const int arow = mt * 16 + lq * 4 + r;
          int u = tb - arow;                       // valid band: [0,32)
          u = u < -2 ? -2 : (u > 34 ? 34 : u);     // invalid -> row padding
          G1f[2 + arow * GP + u] = a[r];
        }
      }
#pragma unroll
      for (int mt = 0; mt < 2; ++mt) {
        f32x4 g = vzero;
        g = __builtin_amdgcn_mfma_f32_16x16x32_bf16(kf[mt][0], qr0, g, 0, 0, 0);
        g = __builtin_amdgcn_mfma_f32_16x16x32_bf16(kf[mt][1], qr1, g, 0, 0, 0);
#pragma unroll
        for (int r = 0; r < 4; ++r) {
          const int brow = mt * 16 + lq * 4 + r;
          int u = tb + brow - 31;                  // valid band: [0,32)
          u = u < -2 ? -2 : (u > 34 ? 34 : u);
          G2f[2 + brow * GP + u] = g[r];
        }
      }
    }

    // ---- no-max softmax (phase 1: reads G1f/G2f, no cross-lane ops) ----
    u32 pk[2][4];
#pragma unroll
    for (int mt = 0; mt < 2; ++mt) {
#pragma unroll
      for (int r = 0; r < 4; ++r) {
        const int a_ = mt * 16 + lq * 4 + r;
        float s0 = cc[mt][0][r] + G1f[2 + a_ * GP + 31 - lr] + G2f[2 + lr * GP + a_];
        float s1 = cc[mt][1][r] + G1f[2 + a_ * GP + 15 - lr] + G2f[2 + (16 + lr) * GP + a_];
        s0 = mv0 ? -1e30f : s0 * kscale;
        s1 = mv1 ? -1e30f : s1 * kscale;
        const float p0 = EXP2(s0);
        const float p1 = EXP2(s1);
        lst[mt][r] += p0 + p1;
        pk[mt][r] = (u32)f2b(p0) | ((u32)f2b(p1) << 16);
      }
    }
    __asm__ volatile("" ::: "memory");  // order: G reads above, Pb stores below
    // ---- phase 2: write Pb (aliases G1f rows) ----
#pragma unroll
    for (int mt = 0; mt < 2; ++mt)
#pragma unroll
      for (int r = 0; r < 4; ++r) {
        const int a_ = mt * 16 + lq * 4 + r;
        Pb[a_ * PBP + lr]      = (u16)pk[mt][r];
        Pb[a_ * PBP + 16 + lr] = (u16)(pk[mt][r] >> 16);
      }

    // ---- V fragments (deferred: loaded only for PV, shortens reg live span)
    bf16x8 vf[4];
#pragma unroll
    for (int n4 = 0; n4 < 4; ++n4)
      vf[n4] = *(const bf16x8*)(vtb + (size_t)(n4 * 16 + lr) * S + j0 + lq * 8);

    // ---- PV: read P A-frags, accumulate (no rescale — unnormalized) ----
#pragma unroll
    for (int mt = 0; mt < 2; ++mt) {
      union { u32 u[4]; bf16x8 v; } pr;
      const u16* prow = Pb + (mt * 16 + lr) * PBP + lq * 8;
      pr.u[0] = *(const u32*)prow;
      pr.u[1] = *(const u32*)(prow + 2);
      pr.u[2] = *(const u32*)(prow + 4);
      pr.u[3] = *(const u32*)(prow + 6);
#pragma unroll
      for (int nd = 0; nd < 4; ++nd)
        o[mt][nd] = __builtin_amdgcn_mfma_f32_16x16x32_bf16(pr.v, vf[nd], o[mt][nd], 0, 0, 0);
    }
    __asm__ volatile("" ::: "memory");  // order: Pb reads above, next-iter band stores below
  }

  // ---- dump per-wave state, merge 4 ways, write ao ----
  {
    float* Orm = (float*)wbase;            // [32][64]
    float* llw = (float*)(wbase + 8192);   // [32]
#pragma unroll
    for (int mt = 0; mt < 2; ++mt)
#pragma unroll
      for (int nd = 0; nd < 4; ++nd)
#pragma unroll
        for (int r = 0; r < 4; ++r)
          Orm[(mt * 16 + lq * 4 + r) * 64 + nd * 16 + lr] = o[mt][nd][r];
#pragma unroll
    for (int mt = 0; mt < 2; ++mt)
#pragma unroll
      for (int r = 0; r < 4; ++r) {
        const float rl = red_sum16(lst[mt][r]);   // row-total l (once, not per iter)
        if (lr == 0) llw[mt * 16 + lq * 4 + r] = rl;
      }
  }
  __syncthreads();
  {
    const int a_ = tid >> 3, d0 = (tid & 7) * 8;
    float L = 0.f, acc[8];
#pragma unroll
    for (int d = 0; d < 8; ++d) acc[d] = 0.f;
#pragma unroll
    for (int w = 0; w < 4; ++w) {
      const char* wb = smem + w * WLDS;
      L += *(const float*)(wb + 8192 + a_ * 4);
      const float* Ow = (const float*)wb + a_ * 64 + d0;
#pragma unroll
      for (int d = 0; d < 8; ++d) acc[d] += Ow[d];
    }
    const float inv = 1.f / L;
    U16x8 pk;
#pragma unroll
    for (int d = 0; d < 8; ++d) pk.s[d] = f2b(acc[d] * inv);
    *(uint4*)(ao + ((size_t)((bb << 10) + i0 + a_) << 10) + (h << 6) + d0) = pk.u;
  }
}

// ---------------------------------------------------------------------------
extern "C" void kernel_launch(void* const* d_in, const int* in_sizes, int n_in,
                              void* d_out, int out_size, void* d_ws, size_t ws_size,
                              hipStream_t stream) {
  const float* x   = (const float*)d_in[0];
  const float* rpe = (const float*)d_in[1];
  const int*   pm  = (const int*)d_in[2];
  const float* Wq  = (const float*)d_in[3];  const float* bq  = (const float*)d_in[4];
  const float* Wk  = (const float*)d_in[5];  const float* bk  = (const float*)d_in[6];
  const float* Wv  = (const float*)d_in[7];  const float* bv  = (const float*)d_in[8];
  const float* Wqr = (const float*)d_in[9];  const float* bqr = (const float*)d_in[10];
  const float* Wkr = (const float*)d_in[11]; const float* bkr = (const float*)d_in[12];
  const float* Wc  = (const float*)d_in[13]; const float* bc  = (const float*)d_in[14];

  const size_t NE = (size_t)2 * 1024 * 1024;  // B*S*D elements
  const size_t WE = (size_t)1024 * 1024;      // D*D elements
  u16* ws = (u16*)d_ws;

  if (ws_size >= (10 * NE + 6 * WE) * sizeof(u16)) {
    u16* q   = ws;          u16* k   = ws + NE;     u16* vT  = ws + 2 * NE;
    u16* qr  = ws + 3 * NE; u16* kr  = ws + 4 * NE;
    u16* xb  = ws + 5 * NE;
    u16* ao  = ws + 5 * NE;  // same slot: xb dead once proj GEMM finishes
    u16* rpb = ws + 6 * NE;
    u16* wb  = ws + 7 * NE;
    u16* Wqb = wb;           u16* Wkb = wb + WE;     u16* Wvb = wb + 2 * WE;
    u16* Wqrb= wb + 3 * WE;  u16* Wkrb= wb + 4 * WE; u16* Wcb = wb + 5 * WE;

    CvtArgs c;
    c.s[0] = x;   c.d[0] = xb;   c.n[0] = (int)NE;
    c.s[1] = rpe; c.d[1] = rpb;  c.n[1] = (int)NE;
    c.s[2] = Wq;  c.d[2] = Wqb;  c.n[2] = (int)WE;
    c.s[3] = Wk;  c.d[3] = Wkb;  c.n[3] = (int)WE;
    c.s[4] = Wv;  c.d[4] = Wvb;  c.n[4] = (int)WE;
    c.s[5] = Wqr; c.d[5] = Wqrb; c.n[5] = (int)WE;
    c.s[6] = Wkr; c.d[6] = Wkrb; c.n[6] = (int)WE;
    c.s[7] = Wc;  c.d[7] = Wcb;  c.n[7] = (int)WE;
    cvt_bf16<<<dim3(1024, 8), 256, 0, stream>>>(c);

    GemmBArgs g;
    g.A[0] = xb;  g.W[0] = Wqb;  g.Bi[0] = bq;  g.C[0] = q;
    g.A[1] = xb;  g.W[1] = Wkb;  g.Bi[1] = bk;  g.C[1] = k;
    g.A[2] = xb;  g.W[2] = Wvb;  g.Bi[2] = bv;  g.C[2] = vT;
    g.A[3] = rpb; g.W[3] = Wqrb; g.Bi[3] = bqr; g.C[3] = qr;
    g.A[4] = rpb; g.W[4] = Wkrb; g.Bi[4] = bkr; g.C[4] = kr;
    g.vtz = 2;
    gemm_lds<128, 128, false><<<dim3(8, 16, 5), 256, 0, stream>>>(g, 2048, 1024, 1024);

    attn_wave<<<dim3(1024), 256, 0, stream>>>(q, k, vT, qr, kr, pm, ao);

    GemmBArgs g2;
    for (int i = 0; i < 5; ++i) { g2.A[i] = ao; g2.W[i] = Wcb; g2.Bi[i] = bc; g2.C[i] = d_out; }
    g2.vtz = -1;
    gemm_lds<64, 64, true><<<dim3(16, 32, 1), 256, 0, stream>>>(g2, 2048, 1024, 1024);
  } else {
    if (ws_size < 6 * NE * sizeof(u16)) return;
    u16* q  = ws;          u16* k  = ws + NE;     u16* vT = ws + 2 * NE;
    u16* qr = ws + 3 * NE; u16* kr = ws + 4 * NE; u16* ao = ws + 5 * NE;

    GemmArgs g;
    g.A[0] = x;   g.W[0] = Wq;  g.Bi[0] = bq;  g.C[0] = q;
    g.A[1] = x;   g.W[1] = Wk;  g.Bi[1] = bk;  g.C[1] = k;
    g.A[2] = x;   g.W[2] = Wv;  g.Bi[2] = bv;  g.C[2] = vT;
    g.A[3] = rpe; g.W[3] = Wqr; g.Bi[3] = bqr; g.C[3] = qr;
    g.A[4] = rpe; g.W[4] = Wkr; g.Bi[4] = bkr; g.C[4] = kr;
    g.vtz = 2;
    gemm5<true, false><<<dim3(8, 16, 5), 256, 0, stream>>>(g, 2048, 1024, 1024);

    attn_wave<<<dim3(1024), 256, 0, stream>>>(q, k, vT, qr, kr, pm, ao);

    GemmArgs g2;
    for (int i = 0; i < 5; ++i) { g2.A[i] = ao; g2.W[i] = Wc; g2.Bi[i] = bc; g2.C[i] = d_out; }
    g2.vtz = -1;
    gemm5<false, true><<<dim3(8, 16, 1), 256, 0, stream>>>(g2, 2048, 1024, 1024);
  }
}